// Round 1
// baseline (286.838 us; speedup 1.0000x reference)
//
#include <hip/hip_runtime.h>
#include <stdint.h>

typedef unsigned long long u64;

constexpr int Bn = 32;    // batch
constexpr int Cn = 512;   // channels (in == out)
constexpr int Ln = 4096;  // length
constexpr int Wn = 8;     // 512 channels / 64 bits = 8 words

// ---------------- kernel 1: pack weights + per-filter scale ----------------
// grid: 512 blocks (one per co), 64 threads (one wave)
__global__ __launch_bounds__(64) void pack_w_kernel(const float* __restrict__ w,
                                                    u64* __restrict__ wp,
                                                    float* __restrict__ sw) {
    const int co = blockIdx.x;
    const int lane = threadIdx.x;
    const float* wrow = w + (size_t)co * Cn * 3;
    float asum = 0.0f;
    for (int wi = 0; wi < Wn; ++wi) {
        const int ci = wi * 64 + lane;
#pragma unroll
        for (int k = 0; k < 3; ++k) {
            const float v = wrow[ci * 3 + k];
            asum += fabsf(v);
            const u64 m = __ballot(v > 0.0f);   // bit per lane = sign(+)
            if (lane == 0) wp[(co * 3 + k) * Wn + wi] = m;
        }
    }
    for (int off = 32; off; off >>= 1) asum += __shfl_xor(asum, off, 64);
    if (lane == 0) sw[co] = asum * (1.0f / (float)(Cn * 3));
}

// ---------------- kernel 2: pack x + per-block |x| partial sums ----------------
// grid: dim3(Ln/256=16, Wn=8, Bn=32), 256 threads
__global__ __launch_bounds__(256) void pack_x_kernel(const float* __restrict__ x,
                                                     u64* __restrict__ xp,
                                                     float* __restrict__ partial) {
    const int b = blockIdx.z, wi = blockIdx.y;
    const int l = blockIdx.x * 256 + threadIdx.x;
    const float* xb = x + ((size_t)b * Cn + wi * 64) * Ln + l;
    u64 word = 0;
    float asum = 0.0f;
#pragma unroll 8
    for (int c = 0; c < 64; ++c) {
        const float v = xb[(size_t)c * Ln];   // coalesced across lanes
        asum += fabsf(v);
        word |= (u64)(v > 0.0f) << c;
    }
    xp[((size_t)b * Wn + wi) * Ln + l] = word;

    // block-reduce asum (deterministic, no atomics)
    for (int off = 32; off; off >>= 1) asum += __shfl_xor(asum, off, 64);
    __shared__ float red[4];
    const int wave = threadIdx.x >> 6, lane = threadIdx.x & 63;
    if (lane == 0) red[wave] = asum;
    __syncthreads();
    if (threadIdx.x == 0)
        partial[b * 128 + wi * 16 + blockIdx.x] = red[0] + red[1] + red[2] + red[3];
}

// ---------------- kernel 3: finalize per-sample scale ----------------
// grid: 32 blocks, 128 threads
__global__ __launch_bounds__(128) void finalize_sx_kernel(const float* __restrict__ partial,
                                                          float* __restrict__ sx) {
    const int b = blockIdx.x;
    float v = partial[b * 128 + threadIdx.x];
    for (int off = 32; off; off >>= 1) v += __shfl_xor(v, off, 64);
    __shared__ float red[2];
    const int wave = threadIdx.x >> 6, lane = threadIdx.x & 63;
    if (lane == 0) red[wave] = v;
    __syncthreads();
    if (threadIdx.x == 0) sx[b] = (red[0] + red[1]) * (1.0f / (float)((size_t)Cn * Ln));
}

// ---------------- kernel 4: XNOR-popcount conv + scale epilogue ----------------
// grid: dim3(Ln/64=64, Cn/64=8, Bn=32), 256 threads (4 waves)
// block computes 64 l-positions x 64 output channels
__global__ __launch_bounds__(256) void conv_kernel(const u64* __restrict__ xp,
                                                   const u64* __restrict__ wp,
                                                   const float* __restrict__ sw,
                                                   const float* __restrict__ sx,
                                                   float* __restrict__ out) {
    __shared__ u64 wq[64 * 24];     // [co_local][k][wi]
    __shared__ float sws[64];

    const int b = blockIdx.z;
    const int c0 = blockIdx.y * 64;
    const int l0 = blockIdx.x * 64;

    for (int i = threadIdx.x; i < 64 * 24; i += 256) wq[i] = wp[(size_t)c0 * 24 + i];
    if (threadIdx.x < 64) sws[threadIdx.x] = sw[c0 + threadIdx.x];
    __syncthreads();

    const int lane = threadIdx.x & 63;
    const int wv = threadIdx.x >> 6;
    const int l = l0 + lane;
    const bool v0 = (l >= 1);
    const bool v2 = (l < Ln - 1);
    const int lm = v0 ? l - 1 : l;   // clamped (result discarded when invalid)
    const int lp = v2 ? l + 1 : l;

    const u64* xpb = xp + (size_t)b * Wn * Ln;
    u64 xq0[8], xq1[8], xq2[8];
#pragma unroll
    for (int wi = 0; wi < 8; ++wi) {
        const u64* p = xpb + (size_t)wi * Ln;
        xq0[wi] = p[lm];
        xq1[wi] = p[l];
        xq2[wi] = p[lp];
    }

    const float sxb = sx[b];
    const size_t obase = ((size_t)b * Cn + c0 + wv * 16) * Ln + l;

#pragma unroll 2
    for (int ci = 0; ci < 16; ++ci) {
        const int col = wv * 16 + ci;
        const u64* wr = &wq[col * 24];   // same address across wave -> LDS broadcast
        int n0 = 0, n1 = 0, n2 = 0;
#pragma unroll
        for (int wi = 0; wi < 8; ++wi) {
            n0 += __popcll(xq0[wi] ^ wr[0 * 8 + wi]);
            n1 += __popcll(xq1[wi] ^ wr[1 * 8 + wi]);
            n2 += __popcll(xq2[wi] ^ wr[2 * 8 + wi]);
        }
        int s = 512 - 2 * n1;
        s += v0 ? (512 - 2 * n0) : 0;
        s += v2 ? (512 - 2 * n2) : 0;
        out[obase + (size_t)ci * Ln] = sxb * sws[col] * (float)s;
    }
}

extern "C" void kernel_launch(void* const* d_in, const int* in_sizes, int n_in,
                              void* d_out, int out_size, void* d_ws, size_t ws_size,
                              hipStream_t stream) {
    const float* x = (const float*)d_in[0];   // [32, 512, 4096] f32
    const float* w = (const float*)d_in[1];   // [512, 512, 3]  f32
    float* out = (float*)d_out;               // [32, 512, 4096] f32

    char* ws = (char*)d_ws;
    const size_t xp_bytes = (size_t)Bn * Wn * Ln * sizeof(u64);   // 8 MiB
    const size_t wp_bytes = (size_t)Cn * 3 * Wn * sizeof(u64);    // 96 KiB
    u64* xp = (u64*)ws;
    u64* wp = (u64*)(ws + xp_bytes);
    float* sw = (float*)(ws + xp_bytes + wp_bytes);
    float* partial = sw + Cn;
    float* sx = partial + Bn * 128;

    pack_w_kernel<<<dim3(Cn), dim3(64), 0, stream>>>(w, wp, sw);
    pack_x_kernel<<<dim3(Ln / 256, Wn, Bn), dim3(256), 0, stream>>>(x, xp, partial);
    finalize_sx_kernel<<<dim3(Bn), dim3(128), 0, stream>>>(partial, sx);
    conv_kernel<<<dim3(Ln / 64, Cn / 64, Bn), dim3(256), 0, stream>>>(xp, wp, sw, sx, out);
}

// Round 2
// 233.385 us; speedup vs baseline: 1.2290x; 1.2290x over previous
//
#include <hip/hip_runtime.h>
#include <stdint.h>

typedef unsigned long long u64;
typedef unsigned int u32;
typedef int i32x4 __attribute__((ext_vector_type(4)));

constexpr int Bn = 32;    // batch
constexpr int Cn = 512;   // channels (in == out)
constexpr int Ln = 4096;  // length
constexpr int Wn = 8;     // 512 channels / 64 bits

// ============================ helpers ============================
__device__ __forceinline__ void gload_lds16(const void* g, void* l) {
    __builtin_amdgcn_global_load_lds(
        (const __attribute__((address_space(1))) u32*)g,
        (__attribute__((address_space(3))) u32*)l, 16, 0, 0);
}

// ===================== MFMA path: pack weights =====================
// grid: 512 (one per co), 64 threads. wq layout: [k][co][ci] i8.
__global__ __launch_bounds__(64) void pack_w_i8_kernel(const float* __restrict__ w,
                                                       char* __restrict__ wq,
                                                       float* __restrict__ sw,
                                                       float* __restrict__ zpad) {
    const int co = blockIdx.x, lane = threadIdx.x;
    if (co == 0) { zpad[lane] = 0.0f; zpad[64 + lane] = 0.0f; }  // 512B zero pad region
    const float* wrow = w + (size_t)co * Cn * 3;
    float asum = 0.0f;
    for (int wi = 0; wi < Wn; ++wi) {
        const int ci = wi * 64 + lane;
        const float v0 = wrow[ci * 3 + 0], v1 = wrow[ci * 3 + 1], v2 = wrow[ci * 3 + 2];
        asum += fabsf(v0) + fabsf(v1) + fabsf(v2);
        wq[(size_t)0 * Cn * Cn + (size_t)co * Cn + ci] = (v0 > 0.0f) ? 1 : -1;
        wq[(size_t)1 * Cn * Cn + (size_t)co * Cn + ci] = (v1 > 0.0f) ? 1 : -1;
        wq[(size_t)2 * Cn * Cn + (size_t)co * Cn + ci] = (v2 > 0.0f) ? 1 : -1;
    }
    for (int off = 32; off; off >>= 1) asum += __shfl_xor(asum, off, 64);
    if (lane == 0) sw[co] = asum * (1.0f / (float)(Cn * 3));
}

// ===================== MFMA path: pack x (transpose to [b][l][ci]) =====================
// grid: dim3(Ln/256=16, Cn/64=8, Bn=32), 256 threads
__global__ __launch_bounds__(256) void pack_x_i8_kernel(const float* __restrict__ x,
                                                        char* __restrict__ xs,
                                                        float* __restrict__ partial) {
    __shared__ __align__(16) char sm[256 * 80];   // [l_local][ci pitch 80]
    __shared__ float red[4];
    const int b = blockIdx.z, ciG = blockIdx.y;
    const int l0 = blockIdx.x * 256, tid = threadIdx.x;
    const int ci0 = ciG * 64;
    const float* xb = x + ((size_t)b * Cn + ci0) * Ln + l0 + tid;
    float asum = 0.0f;
    u32 word = 0;
#pragma unroll 8
    for (int c = 0; c < 64; ++c) {
        const float v = xb[(size_t)c * Ln];          // coalesced across lanes
        asum += fabsf(v);
        word |= (u32)((v > 0.0f) ? 0x01u : 0xFFu) << ((c & 3) * 8);
        if ((c & 3) == 3) { *(u32*)&sm[tid * 80 + (c >> 2) * 4] = word; word = 0; }
    }
    for (int off = 32; off; off >>= 1) asum += __shfl_xor(asum, off, 64);
    if ((tid & 63) == 0) red[tid >> 6] = asum;
    __syncthreads();
    if (tid == 0) partial[b * 128 + ciG * 16 + blockIdx.x] = red[0] + red[1] + red[2] + red[3];
#pragma unroll
    for (int p = 0; p < 4; ++p) {
        const int row = p * 64 + (tid >> 2), ch = tid & 3;
        const i32x4 v = *(const i32x4*)&sm[row * 80 + ch * 16];
        *(i32x4*)(xs + ((size_t)b * Ln + l0 + row) * Cn + ci0 + ch * 16) = v;
    }
}

// ===================== finalize per-sample scale =====================
__global__ __launch_bounds__(128) void finalize_sx_kernel(const float* __restrict__ partial,
                                                          float* __restrict__ sx) {
    const int b = blockIdx.x;
    float v = partial[b * 128 + threadIdx.x];
    for (int off = 32; off; off >>= 1) v += __shfl_xor(v, off, 64);
    __shared__ float red[2];
    if ((threadIdx.x & 63) == 0) red[threadIdx.x >> 6] = v;
    __syncthreads();
    if (threadIdx.x == 0) sx[b] = (red[0] + red[1]) * (1.0f / (float)((size_t)Cn * Ln));
}

// ===================== implicit-GEMM i8 MFMA conv =====================
// grid: 8192 blocks (XCD-swizzled over co_t(4) x lt(64) x b(32)), 256 threads (4 waves, 2x2)
// block tile: 128 co x 64 l, BK=64 ci, 3 taps. LDS: dbuf x (A 24576 + B 66*64=4224) = 57600.
__global__ __launch_bounds__(256) void xgemm_kernel(
    const char* __restrict__ xs, const char* __restrict__ wq,
    const float* __restrict__ sw, const float* __restrict__ sx,
    const float* __restrict__ zpadf, float* __restrict__ out) {
    __shared__ __align__(16) char lds[57600];
    const int tid = threadIdx.x;
    const int lane = tid & 63, wid = tid >> 6;
    const int wr = wid >> 1, wc = wid & 1;
    const int lm = lane & 15, kb = lane >> 4;

    // bijective XCD-aware decode: consecutive ids (same XCD) iterate co tiles first
    const int X = blockIdx.x;
    const int xcd = X & 7, j0 = X >> 3;
    const int co_t = j0 & 3, rest = j0 >> 2;
    const int P = rest * 8 + xcd;
    const int b = P >> 6, lt = P & 63;
    const int c0 = co_t * 128, l0 = lt * 64;

    const char* zpad = (const char*)zpadf;

    // staging sources (ci0=0); chunk index XOR-swizzled so LDS stays linear
    const char* srcA[6];
#pragma unroll
    for (int p = 0; p < 6; ++p) {
        const int c = p * 256 + tid;
        const int tap = c >> 9, r = (c >> 2) & 127, jj = (c & 3) ^ ((r >> 1) & 3);
        srcA[p] = wq + (size_t)tap * Cn * Cn + (size_t)(c0 + r) * Cn + jj * 16;
    }
    const char* srcB[2];
#pragma unroll
    for (int p = 0; p < 2; ++p) {
        const int c = p * 256 + tid;
        const int row = c >> 2, jj = (c & 3) ^ ((row >> 1) & 3);
        const int l = l0 - 1 + row;
        srcB[p] = (l >= 0 && l < Ln) ? xs + ((size_t)b * Ln + l) * Cn + jj * 16 : zpad;
    }

    // fragment LDS offsets (swizzled to match staging)
    int aoff[4];
#pragma unroll
    for (int m = 0; m < 4; ++m) {
        const int cr = wr * 64 + m * 16 + lm;
        aoff[m] = cr * 64 + ((kb ^ ((cr >> 1) & 3)) << 4);
    }
    int boff[2][3];
#pragma unroll
    for (int n = 0; n < 2; ++n)
#pragma unroll
        for (int tap = 0; tap < 3; ++tap) {
            const int lr = wc * 32 + n * 16 + lm + tap;   // tile row = l - (l0-1)
            boff[n][tap] = lr * 64 + ((kb ^ ((lr >> 1) & 3)) << 4);
        }

    i32x4 acc[4][2] = {};

    auto stage = [&](int kt, int tb) {
        char* base = (char*)lds + tb * 28800;
        const int ko = kt * 64;
#pragma unroll
        for (int p = 0; p < 6; ++p)
            gload_lds16(srcA[p] + ko, base + (p * 256 + tid) * 16);
        char* bb = base + 24576;
        gload_lds16(srcB[0] + ko, bb + tid * 16);
        if (tid < 8) gload_lds16(srcB[1] + ko, bb + (256 + tid) * 16);
    };

    auto compute = [&](int tb) {
        const char* A = (const char*)lds + tb * 28800;
        const char* Bt = A + 24576;
#pragma unroll
        for (int tap = 0; tap < 3; ++tap) {
            i32x4 af[4], bf[2];
#pragma unroll
            for (int m = 0; m < 4; ++m) af[m] = *(const i32x4*)(A + tap * 8192 + aoff[m]);
#pragma unroll
            for (int n = 0; n < 2; ++n) bf[n] = *(const i32x4*)(Bt + boff[n][tap]);
#pragma unroll
            for (int m = 0; m < 4; ++m)
#pragma unroll
                for (int n = 0; n < 2; ++n)
                    acc[m][n] = __builtin_amdgcn_mfma_i32_16x16x64_i8(af[m], bf[n], acc[m][n], 0, 0, 0);
        }
    };

    stage(0, 0);
    __syncthreads();
    int buf = 0;
    for (int kt = 0; kt < 8; ++kt) {
        if (kt < 7) stage(kt + 1, buf ^ 1);   // issue next-tile loads before compute
        compute(buf);
        __syncthreads();                       // drains vmcnt+lgkm, flips buffer
        buf ^= 1;
    }

    // epilogue: scale + store. D: col=lane&15 (l), row=(lane>>4)*4+reg (co)
    const float sxb = sx[b];
#pragma unroll
    for (int m = 0; m < 4; ++m) {
        const int cob = c0 + wr * 64 + m * 16 + kb * 4;
        const float4 swv = *(const float4*)(sw + cob);
        const float s0 = sxb * swv.x, s1 = sxb * swv.y, s2 = sxb * swv.z, s3 = sxb * swv.w;
#pragma unroll
        for (int n = 0; n < 2; ++n) {
            const int l = l0 + wc * 32 + n * 16 + lm;
            float* po = out + ((size_t)b * Cn + cob) * Ln + l;
            po[0]              = (float)acc[m][n][0] * s0;
            po[(size_t)Ln]     = (float)acc[m][n][1] * s1;
            po[(size_t)2 * Ln] = (float)acc[m][n][2] * s2;
            po[(size_t)3 * Ln] = (float)acc[m][n][3] * s3;
        }
    }
}

// ===================== fallback popcount path (round-1, passing) =====================
__global__ __launch_bounds__(64) void pack_w_kernel(const float* __restrict__ w,
                                                    u64* __restrict__ wp,
                                                    float* __restrict__ sw) {
    const int co = blockIdx.x;
    const int lane = threadIdx.x;
    const float* wrow = w + (size_t)co * Cn * 3;
    float asum = 0.0f;
    for (int wi = 0; wi < Wn; ++wi) {
        const int ci = wi * 64 + lane;
#pragma unroll
        for (int k = 0; k < 3; ++k) {
            const float v = wrow[ci * 3 + k];
            asum += fabsf(v);
            const u64 m = __ballot(v > 0.0f);
            if (lane == 0) wp[(co * 3 + k) * Wn + wi] = m;
        }
    }
    for (int off = 32; off; off >>= 1) asum += __shfl_xor(asum, off, 64);
    if (lane == 0) sw[co] = asum * (1.0f / (float)(Cn * 3));
}

__global__ __launch_bounds__(256) void pack_x_kernel(const float* __restrict__ x,
                                                     u64* __restrict__ xp,
                                                     float* __restrict__ partial) {
    const int b = blockIdx.z, wi = blockIdx.y;
    const int l = blockIdx.x * 256 + threadIdx.x;
    const float* xb = x + ((size_t)b * Cn + wi * 64) * Ln + l;
    u64 word = 0;
    float asum = 0.0f;
#pragma unroll 8
    for (int c = 0; c < 64; ++c) {
        const float v = xb[(size_t)c * Ln];
        asum += fabsf(v);
        word |= (u64)(v > 0.0f) << c;
    }
    xp[((size_t)b * Wn + wi) * Ln + l] = word;
    for (int off = 32; off; off >>= 1) asum += __shfl_xor(asum, off, 64);
    __shared__ float red[4];
    const int wave = threadIdx.x >> 6, lane = threadIdx.x & 63;
    if (lane == 0) red[wave] = asum;
    __syncthreads();
    if (threadIdx.x == 0)
        partial[b * 128 + wi * 16 + blockIdx.x] = red[0] + red[1] + red[2] + red[3];
}

__global__ __launch_bounds__(256) void conv_kernel(const u64* __restrict__ xp,
                                                   const u64* __restrict__ wp,
                                                   const float* __restrict__ sw,
                                                   const float* __restrict__ sx,
                                                   float* __restrict__ out) {
    __shared__ u64 wq[64 * 24];
    __shared__ float sws[64];
    const int b = blockIdx.z;
    const int c0 = blockIdx.y * 64;
    const int l0 = blockIdx.x * 64;
    for (int i = threadIdx.x; i < 64 * 24; i += 256) wq[i] = wp[(size_t)c0 * 24 + i];
    if (threadIdx.x < 64) sws[threadIdx.x] = sw[c0 + threadIdx.x];
    __syncthreads();
    const int lane = threadIdx.x & 63;
    const int wv = threadIdx.x >> 6;
    const int l = l0 + lane;
    const bool v0 = (l >= 1);
    const bool v2 = (l < Ln - 1);
    const int lmi = v0 ? l - 1 : l;
    const int lp = v2 ? l + 1 : l;
    const u64* xpb = xp + (size_t)b * Wn * Ln;
    u64 xq0[8], xq1[8], xq2[8];
#pragma unroll
    for (int wi = 0; wi < 8; ++wi) {
        const u64* p = xpb + (size_t)wi * Ln;
        xq0[wi] = p[lmi]; xq1[wi] = p[l]; xq2[wi] = p[lp];
    }
    const float sxb = sx[b];
    const size_t obase = ((size_t)b * Cn + c0 + wv * 16) * Ln + l;
#pragma unroll 2
    for (int ci = 0; ci < 16; ++ci) {
        const int col = wv * 16 + ci;
        const u64* wr = &wq[col * 24];
        int n0 = 0, n1 = 0, n2 = 0;
#pragma unroll
        for (int wi = 0; wi < 8; ++wi) {
            n0 += __popcll(xq0[wi] ^ wr[0 * 8 + wi]);
            n1 += __popcll(xq1[wi] ^ wr[1 * 8 + wi]);
            n2 += __popcll(xq2[wi] ^ wr[2 * 8 + wi]);
        }
        int s = 512 - 2 * n1;
        s += v0 ? (512 - 2 * n0) : 0;
        s += v2 ? (512 - 2 * n2) : 0;
        out[obase + (size_t)ci * Ln] = sxb * sws[col] * (float)s;
    }
}

// ============================ launch ============================
extern "C" void kernel_launch(void* const* d_in, const int* in_sizes, int n_in,
                              void* d_out, int out_size, void* d_ws, size_t ws_size,
                              hipStream_t stream) {
    const float* x = (const float*)d_in[0];   // [32, 512, 4096] f32
    const float* w = (const float*)d_in[1];   // [512, 512, 3]  f32
    float* out = (float*)d_out;               // [32, 512, 4096] f32
    char* ws = (char*)d_ws;

    const size_t NEED = 67914368;  // xs 67108864 + wq 786432 + zpad 512 + sw 2048 + sx 128 + partial 16384
    if (ws_size >= NEED) {
        char* xs = ws;                                  // [b][l][ci] i8
        char* wq = ws + 67108864;                       // [k][co][ci] i8
        float* zpad = (float*)(ws + 67895296);          // 512 B zeros
        float* sw = (float*)(ws + 67895808);
        float* sx = (float*)(ws + 67897856);
        float* partial = (float*)(ws + 67897984);

        pack_w_i8_kernel<<<dim3(Cn), dim3(64), 0, stream>>>(w, wq, sw, zpad);
        pack_x_i8_kernel<<<dim3(Ln / 256, Cn / 64, Bn), dim3(256), 0, stream>>>(x, xs, partial);
        finalize_sx_kernel<<<dim3(Bn), dim3(128), 0, stream>>>(partial, sx);
        xgemm_kernel<<<dim3(8192), dim3(256), 0, stream>>>(xs, wq, sw, sx, zpad, out);
    } else {
        const size_t xp_bytes = (size_t)Bn * Wn * Ln * sizeof(u64);
        const size_t wp_bytes = (size_t)Cn * 3 * Wn * sizeof(u64);
        u64* xp = (u64*)ws;
        u64* wp = (u64*)(ws + xp_bytes);
        float* sw = (float*)(ws + xp_bytes + wp_bytes);
        float* partial = sw + Cn;
        float* sx = partial + Bn * 128;

        pack_w_kernel<<<dim3(Cn), dim3(64), 0, stream>>>(w, wp, sw);
        pack_x_kernel<<<dim3(Ln / 256, Wn, Bn), dim3(256), 0, stream>>>(x, xp, partial);
        finalize_sx_kernel<<<dim3(Bn), dim3(128), 0, stream>>>(partial, sx);
        conv_kernel<<<dim3(Ln / 64, Cn / 64, Bn), dim3(256), 0, stream>>>(xp, wp, sw, sx, out);
    }
}

// Round 3
// 198.400 us; speedup vs baseline: 1.4458x; 1.1763x over previous
//
#include <hip/hip_runtime.h>
#include <stdint.h>

typedef unsigned long long u64;
typedef unsigned int u32;
typedef int i32x4 __attribute__((ext_vector_type(4)));

constexpr int Bn = 32;    // batch
constexpr int Cn = 512;   // channels (in == out)
constexpr int Ln = 4096;  // length
constexpr int Wn = 8;     // 512 channels / 64 bits

// ============================ helpers ============================
__device__ __forceinline__ void gload_lds16(const void* g, void* l) {
    __builtin_amdgcn_global_load_lds(
        (const __attribute__((address_space(1))) u32*)g,
        (__attribute__((address_space(3))) u32*)l, 16, 0, 0);
}

// ===================== MFMA path: pack weights =====================
// grid: 512 (one per co), 64 threads. wq layout: [k][co][ci] i8.
__global__ __launch_bounds__(64) void pack_w_i8_kernel(const float* __restrict__ w,
                                                       char* __restrict__ wq,
                                                       float* __restrict__ sw,
                                                       float* __restrict__ zpad) {
    const int co = blockIdx.x, lane = threadIdx.x;
    if (co == 0) { zpad[lane] = 0.0f; zpad[64 + lane] = 0.0f; }  // 512B zero pad region
    const float* wrow = w + (size_t)co * Cn * 3;
    float asum = 0.0f;
    for (int wi = 0; wi < Wn; ++wi) {
        const int ci = wi * 64 + lane;
        const float v0 = wrow[ci * 3 + 0], v1 = wrow[ci * 3 + 1], v2 = wrow[ci * 3 + 2];
        asum += fabsf(v0) + fabsf(v1) + fabsf(v2);
        wq[(size_t)0 * Cn * Cn + (size_t)co * Cn + ci] = (v0 > 0.0f) ? 1 : -1;
        wq[(size_t)1 * Cn * Cn + (size_t)co * Cn + ci] = (v1 > 0.0f) ? 1 : -1;
        wq[(size_t)2 * Cn * Cn + (size_t)co * Cn + ci] = (v2 > 0.0f) ? 1 : -1;
    }
    for (int off = 32; off; off >>= 1) asum += __shfl_xor(asum, off, 64);
    if (lane == 0) sw[co] = asum * (1.0f / (float)(Cn * 3));
}

// ===================== MFMA path: pack x (transpose to [b][l][ci]) =====================
// grid: dim3(Ln/256=16, Cn/64=8, Bn=32), 256 threads
__global__ __launch_bounds__(256) void pack_x_i8_kernel(const float* __restrict__ x,
                                                        char* __restrict__ xs,
                                                        float* __restrict__ partial) {
    __shared__ __align__(16) char sm[256 * 80];   // [l_local][ci pitch 80]
    __shared__ float red[4];
    const int b = blockIdx.z, ciG = blockIdx.y;
    const int l0 = blockIdx.x * 256, tid = threadIdx.x;
    const int ci0 = ciG * 64;
    const float* xb = x + ((size_t)b * Cn + ci0) * Ln + l0 + tid;
    float asum = 0.0f;
    u32 word = 0;
#pragma unroll 8
    for (int c = 0; c < 64; ++c) {
        const float v = xb[(size_t)c * Ln];          // coalesced across lanes
        asum += fabsf(v);
        word |= (u32)((v > 0.0f) ? 0x01u : 0xFFu) << ((c & 3) * 8);
        if ((c & 3) == 3) { *(u32*)&sm[tid * 80 + (c >> 2) * 4] = word; word = 0; }
    }
    for (int off = 32; off; off >>= 1) asum += __shfl_xor(asum, off, 64);
    if ((tid & 63) == 0) red[tid >> 6] = asum;
    __syncthreads();
    if (tid == 0) partial[b * 128 + ciG * 16 + blockIdx.x] = red[0] + red[1] + red[2] + red[3];
#pragma unroll
    for (int p = 0; p < 4; ++p) {
        const int row = p * 64 + (tid >> 2), ch = tid & 3;
        const i32x4 v = *(const i32x4*)&sm[row * 80 + ch * 16];
        *(i32x4*)(xs + ((size_t)b * Ln + l0 + row) * Cn + ci0 + ch * 16) = v;
    }
}

// ===================== finalize per-sample scale =====================
__global__ __launch_bounds__(128) void finalize_sx_kernel(const float* __restrict__ partial,
                                                          float* __restrict__ sx) {
    const int b = blockIdx.x;
    float v = partial[b * 128 + threadIdx.x];
    for (int off = 32; off; off >>= 1) v += __shfl_xor(v, off, 64);
    __shared__ float red[2];
    if ((threadIdx.x & 63) == 0) red[threadIdx.x >> 6] = v;
    __syncthreads();
    if (threadIdx.x == 0) sx[b] = (red[0] + red[1]) * (1.0f / (float)((size_t)Cn * Ln));
}

// ===================== implicit-GEMM i8 MFMA conv =====================
// grid: 4096 blocks (XCD-swizzled over co_t(8) x lt(16) x b(32)), 256 threads (4 waves)
// block tile: 64 co x 256 l; per-wave 64co x 64l (m=4,n=4). BK=64 ci, 3 taps.
// LDS: dbuf x (A [3][64][64]=12288 + B [258][64]=16512) = 57600.
// Pipeline: counted-vmcnt 2-phase (stage next -> vmcnt(L) -> barrier -> compute -> barrier).
__global__ __launch_bounds__(256, 2) void xgemm_kernel(
    const char* __restrict__ xs, const char* __restrict__ wq,
    const float* __restrict__ sw, const float* __restrict__ sx,
    const float* __restrict__ zpadf, float* __restrict__ out) {
    __shared__ __align__(16) char lds[57600];
    const int tid = threadIdx.x;
    const int lane = tid & 63, wid = tid >> 6;
    const int wc = wid;                       // wave owns l-strip wid*64
    const int lm = lane & 15, kb = lane >> 4;

    // bijective XCD-aware decode: within an XCD, co_t iterates fastest (shares B rows)
    const int X = blockIdx.x;
    const int xcd = X & 7, k = X >> 3;
    const int co_t = k & 7;
    const int P = (k >> 3) * 8 + xcd;         // [0,512)
    const int lt = P & 15, b = P >> 4;
    const int c0 = co_t * 64, l0 = lt * 256;

    const char* zpad = (const char*)zpadf;

    // staging sources (ko added per K-step); chunk XOR-swizzled, LDS linear
    const char* srcA[3];
#pragma unroll
    for (int p = 0; p < 3; ++p) {
        const int c = p * 256 + tid;
        const int tap = c >> 8, r = (c >> 2) & 63, jj = (c & 3) ^ ((r >> 1) & 3);
        srcA[p] = wq + (size_t)tap * Cn * Cn + (size_t)(c0 + r) * Cn + jj * 16;
    }
    const char* srcB[4];
#pragma unroll
    for (int p = 0; p < 4; ++p) {
        const int c = p * 256 + tid;
        const int row = c >> 2, jj = (c & 3) ^ ((row >> 1) & 3);
        const int l = l0 - 1 + row;
        srcB[p] = (l >= 0 && l < Ln) ? xs + ((size_t)b * Ln + l) * Cn + jj * 16 : zpad;
    }
    const char* srcB4;
    {
        const int c = 1024 + (lane & 7);
        const int row = c >> 2, jj = (c & 3) ^ ((row >> 1) & 3);
        const int l = l0 - 1 + row;
        srcB4 = (l >= 0 && l < Ln) ? xs + ((size_t)b * Ln + l) * Cn + jj * 16 : zpad;
    }

    // fragment LDS offsets (swizzle matches staging)
    int aoff[4];
#pragma unroll
    for (int m = 0; m < 4; ++m) {
        const int cr = m * 16 + lm;
        aoff[m] = cr * 64 + ((kb ^ ((cr >> 1) & 3)) << 4);
    }
    int boff[4][3];
#pragma unroll
    for (int n = 0; n < 4; ++n)
#pragma unroll
        for (int tap = 0; tap < 3; ++tap) {
            const int rr = wc * 64 + n * 16 + lm + tap;   // tile row = l - (l0-1)
            boff[n][tap] = rr * 64 + ((kb ^ ((rr >> 1) & 3)) << 4);
        }

    i32x4 acc[4][4] = {};

    auto stage = [&](int kt, int tb) {
        char* base = (char*)lds + tb * 28800;
        const int ko = kt * 64;
#pragma unroll
        for (int p = 0; p < 3; ++p)
            gload_lds16(srcA[p] + ko, base + (p * 256 + tid) * 16);
        char* bb = base + 12288;
#pragma unroll
        for (int p = 0; p < 4; ++p)
            gload_lds16(srcB[p] + ko, bb + (p * 256 + tid) * 16);
        if (wid == 0) {                       // scalar branch: only wave 0 issues (count 8)
            if (lane < 8)
                gload_lds16(srcB4 + ko, bb + (1024 + lane) * 16);
        }
    };

    auto compute = [&](int tb) {
        const char* A = (const char*)lds + tb * 28800;
        const char* Bt = A + 12288;
#pragma unroll
        for (int tap = 0; tap < 3; ++tap) {
            i32x4 af[4], bf[4];
#pragma unroll
            for (int m = 0; m < 4; ++m) af[m] = *(const i32x4*)(A + tap * 4096 + aoff[m]);
#pragma unroll
            for (int n = 0; n < 4; ++n) bf[n] = *(const i32x4*)(Bt + boff[n][tap]);
            __builtin_amdgcn_s_setprio(1);
#pragma unroll
            for (int m = 0; m < 4; ++m)
#pragma unroll
                for (int n = 0; n < 4; ++n)
                    acc[m][n] = __builtin_amdgcn_mfma_i32_16x16x64_i8(af[m], bf[n], acc[m][n], 0, 0, 0);
            __builtin_amdgcn_s_setprio(0);
        }
    };

    stage(0, 0);
#pragma unroll
    for (int kt = 0; kt < 8; ++kt) {
        const int buf = kt & 1;
        if (kt < 7) {
            stage(kt + 1, buf ^ 1);           // issue next-tile loads (stay in flight)
            asm volatile("" ::: "memory");
            if (wid == 0) asm volatile("s_waitcnt vmcnt(8)" ::: "memory");
            else          asm volatile("s_waitcnt vmcnt(7)" ::: "memory");
        } else {
            asm volatile("s_waitcnt vmcnt(0)" ::: "memory");
        }
        __builtin_amdgcn_s_barrier();         // buf fully staged for all waves
        asm volatile("" ::: "memory");
        compute(buf);
        asm volatile("" ::: "memory");
        __builtin_amdgcn_s_barrier();         // all waves done reading buf
        asm volatile("" ::: "memory");
    }

    // epilogue: scale + store. D: col=lane&15 (l), row=(lane>>4)*4+reg (co)
    const float sxb = sx[b];
#pragma unroll
    for (int m = 0; m < 4; ++m) {
        const int cob = c0 + m * 16 + kb * 4;
        const float4 swv = *(const float4*)(sw + cob);
        const float s0 = sxb * swv.x, s1 = sxb * swv.y, s2 = sxb * swv.z, s3 = sxb * swv.w;
#pragma unroll
        for (int n = 0; n < 4; ++n) {
            const int l = l0 + wc * 64 + n * 16 + lm;
            float* po = out + ((size_t)b * Cn + cob) * Ln + l;
            po[0]              = (float)acc[m][n][0] * s0;
            po[(size_t)Ln]     = (float)acc[m][n][1] * s1;
            po[(size_t)2 * Ln] = (float)acc[m][n][2] * s2;
            po[(size_t)3 * Ln] = (float)acc[m][n][3] * s3;
        }
    }
}

// ===================== fallback popcount path (round-1, passing) =====================
__global__ __launch_bounds__(64) void pack_w_kernel(const float* __restrict__ w,
                                                    u64* __restrict__ wp,
                                                    float* __restrict__ sw) {
    const int co = blockIdx.x;
    const int lane = threadIdx.x;
    const float* wrow = w + (size_t)co * Cn * 3;
    float asum = 0.0f;
    for (int wi = 0; wi < Wn; ++wi) {
        const int ci = wi * 64 + lane;
#pragma unroll
        for (int k = 0; k < 3; ++k) {
            const float v = wrow[ci * 3 + k];
            asum += fabsf(v);
            const u64 m = __ballot(v > 0.0f);
            if (lane == 0) wp[(co * 3 + k) * Wn + wi] = m;
        }
    }
    for (int off = 32; off; off >>= 1) asum += __shfl_xor(asum, off, 64);
    if (lane == 0) sw[co] = asum * (1.0f / (float)(Cn * 3));
}

__global__ __launch_bounds__(256) void pack_x_kernel(const float* __restrict__ x,
                                                     u64* __restrict__ xp,
                                                     float* __restrict__ partial) {
    const int b = blockIdx.z, wi = blockIdx.y;
    const int l = blockIdx.x * 256 + threadIdx.x;
    const float* xb = x + ((size_t)b * Cn + wi * 64) * Ln + l;
    u64 word = 0;
    float asum = 0.0f;
#pragma unroll 8
    for (int c = 0; c < 64; ++c) {
        const float v = xb[(size_t)c * Ln];
        asum += fabsf(v);
        word |= (u64)(v > 0.0f) << c;
    }
    xp[((size_t)b * Wn + wi) * Ln + l] = word;
    for (int off = 32; off; off >>= 1) asum += __shfl_xor(asum, off, 64);
    __shared__ float red[4];
    const int wave = threadIdx.x >> 6, lane = threadIdx.x & 63;
    if (lane == 0) red[wave] = asum;
    __syncthreads();
    if (threadIdx.x == 0)
        partial[b * 128 + wi * 16 + blockIdx.x] = red[0] + red[1] + red[2] + red[3];
}

__global__ __launch_bounds__(256) void conv_kernel(const u64* __restrict__ xp,
                                                   const u64* __restrict__ wp,
                                                   const float* __restrict__ sw,
                                                   const float* __restrict__ sx,
                                                   float* __restrict__ out) {
    __shared__ u64 wq[64 * 24];
    __shared__ float sws[64];
    const int b = blockIdx.z;
    const int c0 = blockIdx.y * 64;
    const int l0 = blockIdx.x * 64;
    for (int i = threadIdx.x; i < 64 * 24; i += 256) wq[i] = wp[(size_t)c0 * 24 + i];
    if (threadIdx.x < 64) sws[threadIdx.x] = sw[c0 + threadIdx.x];
    __syncthreads();
    const int lane = threadIdx.x & 63;
    const int wv = threadIdx.x >> 6;
    const int l = l0 + lane;
    const bool v0 = (l >= 1);
    const bool v2 = (l < Ln - 1);
    const int lmi = v0 ? l - 1 : l;
    const int lp = v2 ? l + 1 : l;
    const u64* xpb = xp + (size_t)b * Wn * Ln;
    u64 xq0[8], xq1[8], xq2[8];
#pragma unroll
    for (int wi = 0; wi < 8; ++wi) {
        const u64* p = xpb + (size_t)wi * Ln;
        xq0[wi] = p[lmi]; xq1[wi] = p[l]; xq2[wi] = p[lp];
    }
    const float sxb = sx[b];
    const size_t obase = ((size_t)b * Cn + c0 + wv * 16) * Ln + l;
#pragma unroll 2
    for (int ci = 0; ci < 16; ++ci) {
        const int col = wv * 16 + ci;
        const u64* wr = &wq[col * 24];
        int n0 = 0, n1 = 0, n2 = 0;
#pragma unroll
        for (int wi = 0; wi < 8; ++wi) {
            n0 += __popcll(xq0[wi] ^ wr[0 * 8 + wi]);
            n1 += __popcll(xq1[wi] ^ wr[1 * 8 + wi]);
            n2 += __popcll(xq2[wi] ^ wr[2 * 8 + wi]);
        }
        int s = 512 - 2 * n1;
        s += v0 ? (512 - 2 * n0) : 0;
        s += v2 ? (512 - 2 * n2) : 0;
        out[obase + (size_t)ci * Ln] = sxb * sws[col] * (float)s;
    }
}

// ============================ launch ============================
extern "C" void kernel_launch(void* const* d_in, const int* in_sizes, int n_in,
                              void* d_out, int out_size, void* d_ws, size_t ws_size,
                              hipStream_t stream) {
    const float* x = (const float*)d_in[0];   // [32, 512, 4096] f32
    const float* w = (const float*)d_in[1];   // [512, 512, 3]  f32
    float* out = (float*)d_out;               // [32, 512, 4096] f32
    char* ws = (char*)d_ws;

    const size_t NEED = 67914368;  // xs 67108864 + wq 786432 + zpad 512 + sw 2048 + sx 128 + partial 16384
    if (ws_size >= NEED) {
        char* xs = ws;                                  // [b][l][ci] i8
        char* wq = ws + 67108864;                       // [k][co][ci] i8
        float* zpad = (float*)(ws + 67895296);          // 512 B zeros
        float* sw = (float*)(ws + 67895808);
        float* sx = (float*)(ws + 67897856);
        float* partial = (float*)(ws + 67897984);

        pack_w_i8_kernel<<<dim3(Cn), dim3(64), 0, stream>>>(w, wq, sw, zpad);
        pack_x_i8_kernel<<<dim3(Ln / 256, Cn / 64, Bn), dim3(256), 0, stream>>>(x, xs, partial);
        finalize_sx_kernel<<<dim3(Bn), dim3(128), 0, stream>>>(partial, sx);
        xgemm_kernel<<<dim3(4096), dim3(256), 0, stream>>>(xs, wq, sw, sx, zpad, out);
    } else {
        const size_t xp_bytes = (size_t)Bn * Wn * Ln * sizeof(u64);
        const size_t wp_bytes = (size_t)Cn * 3 * Wn * sizeof(u64);
        u64* xp = (u64*)ws;
        u64* wp = (u64*)(ws + xp_bytes);
        float* sw = (float*)(ws + xp_bytes + wp_bytes);
        float* partial = sw + Cn;
        float* sx = partial + Bn * 128;

        pack_w_kernel<<<dim3(Cn), dim3(64), 0, stream>>>(w, wp, sw);
        pack_x_kernel<<<dim3(Ln / 256, Wn, Bn), dim3(256), 0, stream>>>(x, xp, partial);
        finalize_sx_kernel<<<dim3(Bn), dim3(128), 0, stream>>>(partial, sx);
        conv_kernel<<<dim3(Ln / 64, Cn / 64, Bn), dim3(256), 0, stream>>>(xp, wp, sw, sx, out);
    }
}